// Round 13
// baseline (308.975 us; speedup 1.0000x reference)
//
#include <hip/hip_runtime.h>
#include <cstdint>

typedef __attribute__((ext_vector_type(8))) short short8;
typedef __attribute__((ext_vector_type(8))) _Float16 half8;
typedef __attribute__((ext_vector_type(2))) _Float16 h2;
typedef __attribute__((ext_vector_type(2))) __fp16 fp16x2;
typedef __attribute__((ext_vector_type(4))) float f32x4;

#define AS1 __attribute__((address_space(1)))
#define AS3 __attribute__((address_space(3)))

constexpr int NB   = 8;
constexpr int L    = 4096;
constexpr int CH   = 512;     // model dim == E_IN
constexpr int DD   = 64;
constexpr int NE   = 131072;
constexpr int M_ROWS = NB * L;  // 32768
constexpr int WELEM  = CH * CH; // 262144

// VALU-pipe lane reduce (no DS ops)
template <int CTRL>
__device__ __forceinline__ float dppadd(float s) {
    union { float f; int i; } u, r;
    u.f = s;
    r.i = __builtin_amdgcn_update_dpp(0, u.i, CTRL, 0xF, 0xF, true);
    return s + r.f;
}

// ---------------- device bodies (shared by fused + standalone kernels) -------

// f32 -> f16, 8 elems per thread (bid covers 256*8 elems)
__device__ __forceinline__ void cvt_body(int bid, const float* __restrict__ src,
                                         _Float16* __restrict__ dst) {
    const int i = bid * 256 + (int)threadIdx.x;
    const f32x4 a = ((const f32x4*)src)[i * 2];
    const f32x4 b = ((const f32x4*)src)[i * 2 + 1];
    fp16x2 h[4];
    h[0] = __builtin_amdgcn_cvt_pkrtz(a.x, a.y);
    h[1] = __builtin_amdgcn_cvt_pkrtz(a.z, a.w);
    h[2] = __builtin_amdgcn_cvt_pkrtz(b.x, b.y);
    h[3] = __builtin_amdgcn_cvt_pkrtz(b.z, b.w);
    half8 out;
    __builtin_memcpy(&out, h, 16);
    ((half8*)dst)[i] = out;
}

// f16 B^T GEMM body (round-3/11 proven structure).
template <bool OUT_F32>
__device__ __forceinline__ void gemm_body(int bid, _Float16* As, _Float16* Bs,
                                          const _Float16* __restrict__ A,
                                          const _Float16* __restrict__ B,
                                          const float* __restrict__ bias,
                                          void* __restrict__ Cp)
{
    const int swz = (bid & 7) * 128 + (bid >> 3);   // bijective XCD swizzle
    const int row0 = (swz >> 2) * 128;
    const int col0 = (swz & 3) * 128;
    const int t = threadIdx.x, lane = t & 63, wid = t >> 6;
    const int wm = (wid >> 1) * 64, wn = (wid & 1) * 64;
    const int fr = lane & 15, fkb = (lane >> 4) * 8;
    const int srow = lane >> 3;
    const int scol = (lane & 7) * 8;

    f32x4 acc[4][4] = {};

    for (int k0 = 0; k0 < CH; k0 += 64) {
#pragma unroll
        for (int q = 0; q < 4; q++) {
            const int r = wid * 32 + q * 8;
            __builtin_amdgcn_global_load_lds(
                (const AS1 unsigned int*)
                    (A + (size_t)(row0 + r + srow) * CH + k0 + scol),
                (AS3 unsigned int*)(As + r * 64), 16, 0, 0);
        }
#pragma unroll
        for (int q = 0; q < 4; q++) {
            const int r = wid * 32 + q * 8;
            __builtin_amdgcn_global_load_lds(
                (const AS1 unsigned int*)
                    (B + (size_t)(col0 + r + srow) * CH + k0 + scol),
                (AS3 unsigned int*)(Bs + r * 64), 16, 0, 0);
        }
        __syncthreads();
#pragma unroll
        for (int kk = 0; kk < 2; kk++) {
            half8 afr[4], bfr[4];
#pragma unroll
            for (int f = 0; f < 4; f++)
                afr[f] = *(const half8*)&As[(wm + f * 16 + fr) * 64 + kk * 32 + fkb];
#pragma unroll
            for (int f = 0; f < 4; f++)
                bfr[f] = *(const half8*)&Bs[(wn + f * 16 + fr) * 64 + kk * 32 + fkb];
#pragma unroll
            for (int fm = 0; fm < 4; fm++)
#pragma unroll
                for (int fn = 0; fn < 4; fn++)
                    acc[fm][fn] = __builtin_amdgcn_mfma_f32_16x16x32_f16(
                        afr[fm], bfr[fn], acc[fm][fn], 0, 0, 0);
        }
        __syncthreads();
    }

    const int rsub = (lane >> 4) * 4;
#pragma unroll
    for (int fn = 0; fn < 4; fn++) {
        const int gc = col0 + wn + fn * 16 + fr;
        const float bv = bias[gc];
#pragma unroll
        for (int fm = 0; fm < 4; fm++) {
            const int gr = row0 + wm + fm * 16 + rsub;
#pragma unroll
            for (int j = 0; j < 4; j++) {
                const float v = acc[fm][fn][j] + bv;
                if constexpr (OUT_F32)
                    ((float*)Cp)[(size_t)(gr + j) * CH + gc] = v;
                else
                    ((_Float16*)Cp)[(size_t)(gr + j) * CH + gc] = (_Float16)v;
            }
        }
    }
}

// weight convert: idx over 4*WELEM/8 groups, picks source by idx>>15
__device__ __forceinline__ void cvtw_body(int bid, const float* s0, const float* s1,
                                          const float* s2, const float* s3,
                                          _Float16* dst) {
    const int idx = bid * 256 + (int)threadIdx.x;   // 0 .. 131071
    const int wsel = idx >> 15;
    const float* s = (wsel == 0) ? s0 : (wsel == 1) ? s1 : (wsel == 2) ? s2 : s3;
    const int i = idx & 32767;
    const f32x4 a = ((const f32x4*)s)[i * 2];
    const f32x4 b = ((const f32x4*)s)[i * 2 + 1];
    fp16x2 h[4];
    h[0] = __builtin_amdgcn_cvt_pkrtz(a.x, a.y);
    h[1] = __builtin_amdgcn_cvt_pkrtz(a.z, a.w);
    h[2] = __builtin_amdgcn_cvt_pkrtz(b.x, b.y);
    h[3] = __builtin_amdgcn_cvt_pkrtz(b.z, b.w);
    half8 out;
    __builtin_memcpy(&out, h, 16);
    ((half8*)(dst + (size_t)wsel * WELEM))[i] = out;
}

// zero cnt/fill AND the 64-int ecol pad (speculative reads reach NE+56)
__device__ __forceinline__ void zero_body(int bid, int* cnt, int* fill, int* ecol) {
    const int i = bid * 256 + (int)threadIdx.x;
    if (i < L) { cnt[i] = 0; fill[i] = 0; }
    if (i < 64) ecol[NE + i] = 0;
}
__device__ __forceinline__ void count_body(int bid, const int* adj, int* cnt) {
    const int e = bid * 256 + (int)threadIdx.x;
    if (e < NE) atomicAdd(&cnt[adj[e]], 1);
}
__device__ __forceinline__ void scan_body(const int* cnt, int* rowptr) {
    const int lane = threadIdx.x;      // first wave only
    if (lane >= 64) return;
    const int base = lane * 64;
    int s = 0;
    for (int t2 = 0; t2 < 64; t2++) s += cnt[base + t2];
    int incl = s;
    for (int off = 1; off < 64; off <<= 1) {
        int v = __shfl_up(incl, off);
        if (lane >= off) incl += v;
    }
    int run = incl - s;   // exclusive prefix
    for (int t2 = 0; t2 < 64; t2++) { rowptr[base + t2] = run; run += cnt[base + t2]; }
    if (lane == 63) rowptr[L] = run;
}
__device__ __forceinline__ void scatter_body(int bid, const int* adj, const int* rowptr,
                                             int* fill, int* ecol) {
    const int e = bid * 256 + (int)threadIdx.x;
    if (e < NE) {
        int rr = adj[e];
        int pos = rowptr[rr] + atomicAdd(&fill[rr], 1);
        ecol[pos] = adj[NE + e];
    }
}

// ---------------- fused dispatches (overlap path) ----------------
// D0: cvtQ(8192) | cvtw(512) | zero(16)
__global__ __launch_bounds__(256)
void fusedD0(const float* __restrict__ queries, _Float16* __restrict__ stgA,
             const float* Wq, const float* Wk, const float* Wv, const float* Wfc,
             _Float16* __restrict__ wf, int* cnt, int* fill, int* ecol)
{
    const int bid = blockIdx.x;
    if (bid < 8192)       cvt_body(bid, queries, stgA);
    else if (bid < 8704)  cvtw_body(bid - 8192, Wq, Wk, Wv, Wfc, wf);
    else                  zero_body(bid - 8704, cnt, fill, ecol);
}

// D1: gemmQ(1024) | cvtK(8192) | count(512)
__global__ __launch_bounds__(256)
void fusedD1(const _Float16* __restrict__ stgA, const _Float16* __restrict__ wf,
             const float* __restrict__ bq, _Float16* __restrict__ qb,
             const float* __restrict__ keys, _Float16* __restrict__ stgB,
             const int* __restrict__ adj, int* cnt)
{
    __shared__ _Float16 As[128 * 64];
    __shared__ _Float16 Bs[128 * 64];
    const int bid = blockIdx.x;
    if (bid < 1024)       gemm_body<false>(bid, As, Bs, stgA, wf, bq, qb);
    else if (bid < 9216)  cvt_body(bid - 1024, keys, stgB);
    else                  count_body(bid - 9216, adj, cnt);
}

// D2: gemmK(1024) | cvtV(8192) | scan(1)
__global__ __launch_bounds__(256)
void fusedD2(const _Float16* __restrict__ stgB, const _Float16* __restrict__ wf,
             const float* __restrict__ bk, _Float16* __restrict__ kb,
             const float* __restrict__ values, _Float16* __restrict__ stgA,
             const int* __restrict__ cnt, int* rowptr)
{
    __shared__ _Float16 As[128 * 64];
    __shared__ _Float16 Bs[128 * 64];
    const int bid = blockIdx.x;
    if (bid < 1024)       gemm_body<false>(bid, As, Bs, stgB, wf, bk, kb);
    else if (bid < 9216)  cvt_body(bid - 1024, values, stgA);
    else                  scan_body(cnt, rowptr);
}

// D3: gemmV(1024) | scatter(512)
__global__ __launch_bounds__(256)
void fusedD3(const _Float16* __restrict__ stgA, const _Float16* __restrict__ wf,
             const float* __restrict__ bv, _Float16* __restrict__ vb,
             const int* __restrict__ adj, const int* __restrict__ rowptr,
             int* fill, int* ecol)
{
    __shared__ _Float16 As[128 * 64];
    __shared__ _Float16 Bs[128 * 64];
    const int bid = blockIdx.x;
    if (bid < 1024)  gemm_body<false>(bid, As, Bs, stgA, wf, bv, vb);
    else             scatter_body(bid - 1024, adj, rowptr, fill, ecol);
}

// ---------------- standalone kernels (serial fallback + shared) ----------------
__global__ __launch_bounds__(256)
void cvt8_k(const float* __restrict__ src, _Float16* __restrict__ dst) {
    cvt_body(blockIdx.x, src, dst);
}
__global__ __launch_bounds__(256)
void cvtw_k(const float* Wq, const float* Wk, const float* Wv, const float* Wfc,
            _Float16* wf) {
    cvtw_body(blockIdx.x, Wq, Wk, Wv, Wfc, wf);
}
__global__ __launch_bounds__(256)
void zero_k(int* cnt, int* fill, int* ecol) { zero_body(blockIdx.x, cnt, fill, ecol); }
__global__ __launch_bounds__(256)
void count_k(const int* adj, int* cnt) { count_body(blockIdx.x, adj, cnt); }
__global__ __launch_bounds__(256)
void scan_k(const int* cnt, int* rowptr) { scan_body(cnt, rowptr); }
__global__ __launch_bounds__(256)
void scatter_k(const int* adj, const int* rowptr, int* fill, int* ecol) {
    scatter_body(blockIdx.x, adj, rowptr, fill, ecol);
}
template <bool OUT_F32>
__global__ __launch_bounds__(256)
void gemm_f16(const _Float16* __restrict__ A, const _Float16* __restrict__ B,
              const float* __restrict__ bias, void* __restrict__ Cp)
{
    __shared__ _Float16 As[128 * 64];
    __shared__ _Float16 Bs[128 * 64];
    gemm_body<OUT_F32>(blockIdx.x, As, Bs, A, B, bias, Cp);
}

// ---------------- fused edge-softmax + SPMM ----------------
// Round-11 structure; ecol 64-int zero pad makes all speculative index reads
// unconditional (no min clamps); dot chains split 2+2 fdot2 (shorter critical
// path). block = (i, n, hg): 4 waves, wave w = head hg*4+w; XCD pin n=bid&7.
__global__ __launch_bounds__(256)
void attn_k(const _Float16* __restrict__ qb, const _Float16* __restrict__ kb,
            const _Float16* __restrict__ vb, const int* __restrict__ rowptr,
            const int* __restrict__ ecol, _Float16* __restrict__ agg)
{
    __shared__ float part[4 * 8 * 65];
    const int bid = blockIdx.x;
    const int n   = bid & 7;
    const int rem = bid >> 3;
    const int hg  = rem >> 12;
    const int i   = rem & 4095;
    const int lane = threadIdx.x & 63;
    const int w    = threadIdx.x >> 6;
    const int h    = hg * 4 + w;
    const int g    = lane & 7;
    const int grp  = lane >> 3;
    const size_t rowbase = ((size_t)(n * L + i)) * CH + h * DD;

    fp16x2 qq[4];
    {
        const half8 qu = *(const half8*)(qb + rowbase + g * 8);
        const _Float16 sc = (_Float16)(0.125f * 1.44269504088896f);
        h2 qh[4];
#pragma unroll
        for (int e = 0; e < 4; e++) {
            qh[e][0] = qu[2 * e] * sc;
            qh[e][1] = qu[2 * e + 1] * sc;
        }
        __builtin_memcpy(qq, qh, 16);
    }
    const int start = rowptr[i], end = rowptr[i + 1];
    const char* kb_u = (const char*)(kb + (size_t)n * L * CH + h * DD);
    const char* vb_u = (const char*)(vb + (size_t)n * L * CH + h * DD);
    const int goff = g << 4;

    h2 oA[4] = {}, oB[4] = {};
    float lsA = 0.f, lsB = 0.f;

    const int nIt = (end - start + 15) >> 4;   // 16 edges per wave-iter
    int idx = start + grp;
    half8 kA{}, vA{}, kB{}, vB{};
    int jA1 = 0, jB1 = 0;
    if (nIt > 0) {
        // pad-backed: all speculative ecol reads are in-bounds (<= NE+56)
        const int jA0 = ecol[idx];
        const int jB0 = ecol[idx + 8];
        kA = *(const half8*)(kb_u + ((jA0 << 10) + goff));
        vA = *(const half8*)(vb_u + ((jA0 << 10) + goff));
        kB = *(const half8*)(kb_u + ((jB0 << 10) + goff));
        vB = *(const half8*)(vb_u + ((jB0 << 10) + goff));
        jA1 = ecol[idx + 16];
        jB1 = ecol[idx + 24];
    }

    for (int it = 0; it < nIt; ++it) {
        const half8 kAn = *(const half8*)(kb_u + ((jA1 << 10) + goff));
        const half8 vAn = *(const half8*)(vb_u + ((jA1 << 10) + goff));
        const half8 kBn = *(const half8*)(kb_u + ((jB1 << 10) + goff));
        const half8 vBn = *(const half8*)(vb_u + ((jB1 << 10) + goff));
        const int jA2 = ecol[idx + 32];
        const int jB2 = ecol[idx + 40];
        const bool vdA = idx < end;
        const bool vdB = idx + 8 < end;
        fp16x2 ka[4], kb2[4];
        __builtin_memcpy(ka, &kA, 16);
        __builtin_memcpy(kb2, &kB, 16);
        // split dot chains: 2+2 fdot2 per edge, combine once
        float sA0 = 0.f, sA1 = 0.f, sB0 = 0.f, sB1 = 0.f;
#if __has_builtin(__builtin_amdgcn_fdot2)
        sA0 = __builtin_amdgcn_fdot2(ka[0],  qq[0], sA0, false);
        sA1 = __builtin_amdgcn_fdot2(ka[1],  qq[1], sA1, false);
        sA0 = __builtin_amdgcn_fdot2(ka[2],  qq[2], sA0, false);
        sA1 = __builtin_amdgcn_fdot2(ka[3],  qq[3], sA1, false);
        sB0 = __builtin_amdgcn_fdot2(kb2[0], qq[0], sB0, false);
        sB1 = __builtin_amdgcn_fdot2(kb2[1], qq[1], sB1, false);
        sB0 = __builtin_amdgcn_fdot2(kb2[2], qq[2], sB0, false);
        sB1 = __builtin_amdgcn_fdot2(kb2[3], qq[3], sB1, false);
#else
#pragma unroll
        for (int e = 0; e < 4; e++) {
            sA0 = fmaf((float)ka[e][0],  (float)qq[e][0], sA0);
            sA1 = fmaf((float)ka[e][1],  (float)qq[e][1], sA1);
            sB0 = fmaf((float)kb2[e][0], (float)qq[e][0], sB0);
            sB1 = fmaf((float)kb2[e][1], (float)qq[e][1], sB1);
        }
#endif
        float sA = sA0 + sA1, sB = sB0 + sB1;
        sA = dppadd<0xB1>(sA);  sB = dppadd<0xB1>(sB);
        sA = dppadd<0x4E>(sA);  sB = dppadd<0x4E>(sB);
        sA = dppadd<0x141>(sA); sB = dppadd<0x141>(sB);
        float peA = exp2f(sA); peA = vdA ? peA : 0.f;
        float peB = exp2f(sB); peB = vdB ? peB : 0.f;
        const _Float16 phA = (_Float16)peA, phB = (_Float16)peB;
        const h2 pa2 = {phA, phA}, pb2 = {phB, phB};
        h2 va2[4], vb2[4];
        __builtin_memcpy(va2, &vA, 16);
        __builtin_memcpy(vb2, &vB, 16);
#pragma unroll
        for (int e = 0; e < 4; e++) {
            oA[e] += pa2 * va2[e];
            oB[e] += pb2 * vb2[e];
        }
        lsA += peA; lsB += peB;
        kA = kAn; vA = vAn; kB = kBn; vB = vBn;
        jA1 = jA2; jB1 = jB2; idx += 16;
    }

    float lsum = lsA + lsB;
    lsum += __shfl_xor(lsum, 8);
    lsum += __shfl_xor(lsum, 16);
    lsum += __shfl_xor(lsum, 32);

    float o[8];
#pragma unroll
    for (int e = 0; e < 4; e++) {
        o[2 * e]     = (float)oA[e][0] + (float)oB[e][0];
        o[2 * e + 1] = (float)oA[e][1] + (float)oB[e][1];
    }
    float* p = part + w * (8 * 65);
    float* pw = p + grp * 65 + g * 8;
    *(f32x4*)(pw)     = *(f32x4*)&o[0];
    *(f32x4*)(pw + 4) = *(f32x4*)&o[4];
    __builtin_amdgcn_s_waitcnt(0);
    float osum = 0.f;
#pragma unroll
    for (int gg = 0; gg < 8; gg++)
        osum += p[gg * 65 + lane];

    const float inv = (end > start) ? 1.f / lsum : 0.f;
    agg[rowbase + lane] = (_Float16)(osum * inv);
}

extern "C" void kernel_launch(void* const* d_in, const int* in_sizes, int n_in,
                              void* d_out, int out_size, void* d_ws, size_t ws_size,
                              hipStream_t stream)
{
    (void)in_sizes; (void)n_in; (void)out_size;
    const float* queries = (const float*)d_in[0];
    const float* keys    = (const float*)d_in[1];
    const float* values  = (const float*)d_in[2];
    const int*   adj     = (const int*)d_in[3];
    const float* Wq  = (const float*)d_in[4];
    const float* bq  = (const float*)d_in[5];
    const float* Wk  = (const float*)d_in[6];
    const float* bk  = (const float*)d_in[7];
    const float* Wv  = (const float*)d_in[8];
    const float* bv  = (const float*)d_in[9];
    const float* Wfc = (const float*)d_in[10];
    const float* bfc = (const float*)d_in[11];

    _Float16* qb = (_Float16*)d_out;                   // 33.5 MB (d_out dead until final)
    _Float16* kb = qb + (size_t)M_ROWS * CH;           // 33.5 MB
    uint8_t* w = (uint8_t*)d_ws;
    _Float16* vb   = (_Float16*)(w);                              // 33.5 MB
    _Float16* stgA = (_Float16*)(w + 33554432);                   // 33.5 MB (agg aliases)
    _Float16* agg  = stgA;
    _Float16* wf   = (_Float16*)(w + 67108864);                   // 2 MB (4 weights)
    int* cnt    = (int*)(w + 69206016);
    int* fill   = (int*)(w + 69206016 + 16384);
    int* rowptr = (int*)(w + 69206016 + 32768);
    int* ecol   = (int*)(w + 69206016 + 65536);                   // 512 KB + 256 B pad
    _Float16* stgB = (_Float16*)(w + 69799936);                   // +4 KB guard after ecol pad
    constexpr size_t WS_NEED = 69799936ull + 33554432ull;         // 103,354,368

    if (ws_size >= WS_NEED) {
        // ---- overlap path: 6 dispatches ----
        fusedD0<<<dim3(8720), 256, 0, stream>>>(queries, stgA, Wq, Wk, Wv, Wfc,
                                                wf, cnt, fill, ecol);
        fusedD1<<<dim3(9728), 256, 0, stream>>>(stgA, wf + 0 * WELEM, bq, qb,
                                                keys, stgB, adj, cnt);
        fusedD2<<<dim3(9217), 256, 0, stream>>>(stgB, wf + 1 * WELEM, bk, kb,
                                                values, stgA, cnt, rowptr);
        fusedD3<<<dim3(1536), 256, 0, stream>>>(stgA, wf + 2 * WELEM, bv, vb,
                                                adj, rowptr, fill, ecol);
        attn_k<<<dim3(2 * NB * L), 256, 0, stream>>>(qb, kb, vb, rowptr, ecol, agg);
        gemm_f16<true><<<dim3(1024), 256, 0, stream>>>(agg, wf + 3 * WELEM, bfc,
                                                       (float*)d_out);
    } else {
        // ---- serial fallback (round-11 proven order, single staging) ----
        _Float16* stg = stgA;
        cvtw_k<<<dim3(512), 256, 0, stream>>>(Wq, Wk, Wv, Wfc, wf);
        zero_k<<<dim3(16), 256, 0, stream>>>(cnt, fill, ecol);
        count_k<<<dim3(512), 256, 0, stream>>>(adj, cnt);
        scan_k<<<dim3(1), 256, 0, stream>>>(cnt, rowptr);
        scatter_k<<<dim3(512), 256, 0, stream>>>(adj, rowptr, fill, ecol);
        cvt8_k<<<dim3(8192), 256, 0, stream>>>(queries, stg);
        gemm_f16<false><<<dim3(1024), 256, 0, stream>>>(stg, wf + 0 * WELEM, bq, qb);
        cvt8_k<<<dim3(8192), 256, 0, stream>>>(keys, stg);
        gemm_f16<false><<<dim3(1024), 256, 0, stream>>>(stg, wf + 1 * WELEM, bk, kb);
        cvt8_k<<<dim3(8192), 256, 0, stream>>>(values, stg);
        gemm_f16<false><<<dim3(1024), 256, 0, stream>>>(stg, wf + 2 * WELEM, bv, vb);
        attn_k<<<dim3(2 * NB * L), 256, 0, stream>>>(qb, kb, vb, rowptr, ecol, agg);
        gemm_f16<true><<<dim3(1024), 256, 0, stream>>>(agg, wf + 3 * WELEM, bfc,
                                                       (float*)d_out);
    }
}